// Round 4
// baseline (594.822 us; speedup 1.0000x reference)
//
#include <hip/hip_runtime.h>
#include <hip/hip_bf16.h>
#include <math.h>

#define EMBED 1024
#define FFN   4096
#define NW    8
#define MTOT  32768   // 16*2048

#define BM 256
#define BN 128
#define BK 64
#define NT (FFN / BK)   // 64 K-tiles

#define STRIP 128
#define KPT   8

typedef __attribute__((ext_vector_type(8))) short          short8v;
typedef __attribute__((ext_vector_type(8))) unsigned short ushort8v;
typedef __attribute__((ext_vector_type(4))) float          f32x4;

typedef __attribute__((address_space(1))) void gvoid_t;
typedef __attribute__((address_space(3))) void svoid_t;

#define VMCNT(n)  asm volatile("s_waitcnt vmcnt(" #n ")" ::: "memory")
#define SCHEDB()  __builtin_amdgcn_sched_barrier(0)
#define BAR()     __builtin_amdgcn_s_barrier()

static __device__ __forceinline__ unsigned short bf16bits(float f) {
    __hip_bfloat16 h = __float2bfloat16(f);
    return *reinterpret_cast<unsigned short*>(&h);
}

// ---------------- W2 f32 -> bf16 (once, into ws) ----------------
__global__ __launch_bounds__(256) void cvtW2_kernel(const float* __restrict__ W2,
                                                    __hip_bfloat16* __restrict__ Bw) {
    const long i0 = ((long)blockIdx.x * 256 + threadIdx.x) * 8;
    const float4 a = *(const float4*)(W2 + i0);
    const float4 b = *(const float4*)(W2 + i0 + 4);
    float fs[8] = {a.x, a.y, a.z, a.w, b.x, b.y, b.z, b.w};
    ushort8v v;
#pragma unroll
    for (int t = 0; t < 8; ++t) v[t] = bf16bits(fs[t]);
    *reinterpret_cast<ushort8v*>(Bw + i0) = v;
}

// ---------------- producer: h[m,k] = relu(b1[k] + qz[m,:]·W1[k,:]) ----------------
__global__ __launch_bounds__(256) void hprod2_kernel(
    const float* __restrict__ x, const float* __restrict__ theta,
    const float* __restrict__ W1, const float* __restrict__ b1,
    __hip_bfloat16* __restrict__ h, int m0)
{
    __shared__ float qz_lds[STRIP][NW];
    const int tid   = threadIdx.x;
    const int khalf = blockIdx.x & 1;
    const int strip = blockIdx.x >> 1;
    const int k0    = khalf * 2048 + tid * KPT;

    float w1r[KPT][NW];
    float b1r[KPT];
#pragma unroll
    for (int i = 0; i < KPT; ++i) {
        const float4 a = *(const float4*)(W1 + (long)(k0 + i) * NW);
        const float4 b = *(const float4*)(W1 + (long)(k0 + i) * NW + 4);
        w1r[i][0] = a.x; w1r[i][1] = a.y; w1r[i][2] = a.z; w1r[i][3] = a.w;
        w1r[i][4] = b.x; w1r[i][5] = b.y; w1r[i][6] = b.z; w1r[i][7] = b.w;
        b1r[i] = b1[k0 + i];
    }

    if (tid < STRIP) {
        const long m = (long)m0 + (long)strip * STRIP + tid;
        const float* xr = x + m * (long)EMBED;
#pragma unroll
        for (int w = 0; w < NW; ++w)
            qz_lds[tid][w] = cosf(xr[w]) * cosf(theta[w]);
    }
    __syncthreads();

    __hip_bfloat16* hp = h + ((long)strip * STRIP) * FFN + k0;
    for (int r = 0; r < STRIP; ++r) {
        float q[NW];
#pragma unroll
        for (int w = 0; w < NW; ++w) q[w] = qz_lds[r][w];
        ushort8v hv;
#pragma unroll
        for (int i = 0; i < KPT; ++i) {
            float acc = b1r[i];
#pragma unroll
            for (int w = 0; w < NW; ++w) acc = fmaf(q[w], w1r[i][w], acc);
            hv[i] = bf16bits(fmaxf(acc, 0.0f));
        }
        *reinterpret_cast<ushort8v*>(hp + (long)r * FFN) = hv;
    }
}

// ---------------- GEMM v4: 3-deep pipeline, 1 barrier + vmcnt(6) per K-tile ----
// out[M,1024] = h[M,4096] @ W2bf[1024,4096]^T + b2
// BM=256 BN=128 BK=64; 8 waves (2M x 4N), 512 thr; wave owns 128x32 (8mi x 2ni).
// LDS: A 3x32KB + B 3x16KB = 144KB -> 1 block/CU (2 waves/SIMD, m201 regime).
// Per tile t: [vmcnt(6); barrier] -> stage A(t+2) -> p0{ds_read A0-3,B; 16 MFMA}
//             -> stage B(t+2) -> p1{ds_read A4-7; 16 MFMA}.
// FIFO proof: 6 loads/thread/tile (A4+B2); at tile t's vmcnt(6) the newest 6
// in flight = tile t+1's => tile t landed. Buffer (t+2)%3 holds tile t-1,
// whose reads retired before the barrier => overwrite-safe. Never vmcnt(0)
// in steady state (T4); setprio around MFMA clusters (T5).
// G4 XOR swizzle: LDS elem ^= (row&7)<<3, via pre-swizzled GLOBAL source
// (linear LDS dest, global_load_lds-compatible) + swizzled ds_read address.
__global__ __launch_bounds__(512, 2) void gemm4_kernel(
    const __hip_bfloat16* __restrict__ A,   // [rows][FFN] chunk-local h
    const __hip_bfloat16* __restrict__ Bw,  // [EMBED][FFN] W2 bf16
    const float* __restrict__ b2,
    float* __restrict__ out, long m0, int nPm)
{
    __shared__ __align__(16) __hip_bfloat16 As[3][BM * BK];  // 96 KB
    __shared__ __align__(16) __hip_bfloat16 Bs[3][BN * BK];  // 48 KB

    const int tid = threadIdx.x, wid = tid >> 6, lane = tid & 63;
    const int l15 = lane & 15, l4 = lane >> 4;
    const int wr = wid >> 2, wc = wid & 3;          // 2M x 4N

    // bid = pn*nPm + pm, nPm%8==0 => bid&7 == pm&7: all 8 pn of a pm share an
    // XCD -> A panel (2MB) L2-resident, fetched once.
    const int pm = blockIdx.x % nPm, pn = blockIdx.x / nPm;

    // staging lane geometry (global_load_lds writes base + lane*16B, linear)
    const int sr     = lane >> 3;                        // row within 8-row chunk
    const int col_sw = ((lane & 7) ^ sr) * 8;            // pre-swizzled col (elems)

    const __hip_bfloat16* Ag[4];
#pragma unroll
    for (int j = 0; j < 4; ++j)
        Ag[j] = A + (long)(pm * BM + (wid * 4 + j) * 8 + sr) * FFN + col_sw;
    const __hip_bfloat16* Bg[2];
#pragma unroll
    for (int j = 0; j < 2; ++j)
        Bg[j] = Bw + (long)(pn * BN + (wid * 2 + j) * 8 + sr) * FFN + col_sw;

    f32x4 acc[8][2];
#pragma unroll
    for (int i = 0; i < 8; ++i)
#pragma unroll
        for (int j = 0; j < 2; ++j) acc[i][j] = (f32x4){0.f, 0.f, 0.f, 0.f};

#define STAGE_A(t) do {                                                         \
    __hip_bfloat16* _s = &As[(t) % 3][wid * 4 * 8 * BK];                        \
    _Pragma("unroll")                                                           \
    for (int _j = 0; _j < 4; ++_j)                                              \
        __builtin_amdgcn_global_load_lds((gvoid_t*)(Ag[_j] + (t) * BK),         \
                                         (svoid_t*)(_s + _j * 8 * BK), 16, 0, 0); \
} while (0)

#define STAGE_B(t) do {                                                         \
    __hip_bfloat16* _s = &Bs[(t) % 3][wid * 2 * 8 * BK];                        \
    _Pragma("unroll")                                                           \
    for (int _j = 0; _j < 2; ++_j)                                              \
        __builtin_amdgcn_global_load_lds((gvoid_t*)(Bg[_j] + (t) * BK),         \
                                         (svoid_t*)(_s + _j * 8 * BK), 16, 0, 0); \
} while (0)

    // prologue: tiles 0 and 1 (FIFO order = steady-state order: A then B)
    STAGE_A(0); STAGE_B(0); STAGE_A(1); STAGE_B(1);

    const int rxA = (l15 & 7) << 3;   // read-side XOR (row&7)<<3; row&7 == l15&7

    for (int t = 0; t < NT; ++t) {
        if (t < NT - 1) { VMCNT(6); } else { VMCNT(0); }
        SCHEDB(); BAR(); SCHEDB();     // tile t present in LDS for all waves

        const __hip_bfloat16* as = As[t % 3];
        const __hip_bfloat16* bs = Bs[t % 3];

        if (t + 2 < NT) STAGE_A(t + 2);

        // ---- phase 0: mi 0-3 ----
        short8v av0[4][2], bv[2][2];
#pragma unroll
        for (int ni = 0; ni < 2; ++ni)
#pragma unroll
            for (int kk = 0; kk < 2; ++kk) {
                const int row = wc * 32 + ni * 16 + l15;
                bv[ni][kk] = *reinterpret_cast<const short8v*>(
                    &bs[row * BK + ((kk * 32 + l4 * 8) ^ rxA)]);
            }
#pragma unroll
        for (int mi = 0; mi < 4; ++mi)
#pragma unroll
            for (int kk = 0; kk < 2; ++kk) {
                const int row = wr * 128 + mi * 16 + l15;
                av0[mi][kk] = *reinterpret_cast<const short8v*>(
                    &as[row * BK + ((kk * 32 + l4 * 8) ^ rxA)]);
            }
        __builtin_amdgcn_s_setprio(1);
#pragma unroll
        for (int mi = 0; mi < 4; ++mi)
#pragma unroll
            for (int ni = 0; ni < 2; ++ni)
#pragma unroll
                for (int kk = 0; kk < 2; ++kk)
                    acc[mi][ni] = __builtin_amdgcn_mfma_f32_16x16x32_bf16(
                        av0[mi][kk], bv[ni][kk], acc[mi][ni], 0, 0, 0);
        __builtin_amdgcn_s_setprio(0);

        if (t + 2 < NT) STAGE_B(t + 2);

        // ---- phase 1: mi 4-7 ----
        short8v av1[4][2];
#pragma unroll
        for (int mi = 0; mi < 4; ++mi)
#pragma unroll
            for (int kk = 0; kk < 2; ++kk) {
                const int row = wr * 128 + (mi + 4) * 16 + l15;
                av1[mi][kk] = *reinterpret_cast<const short8v*>(
                    &as[row * BK + ((kk * 32 + l4 * 8) ^ rxA)]);
            }
        __builtin_amdgcn_s_setprio(1);
#pragma unroll
        for (int mi = 0; mi < 4; ++mi)
#pragma unroll
            for (int ni = 0; ni < 2; ++ni)
#pragma unroll
                for (int kk = 0; kk < 2; ++kk)
                    acc[mi + 4][ni] = __builtin_amdgcn_mfma_f32_16x16x32_bf16(
                        av1[mi][kk], bv[ni][kk], acc[mi + 4][ni], 0, 0, 0);
        __builtin_amdgcn_s_setprio(0);
    }

#undef STAGE_A
#undef STAGE_B

    // epilogue: + b2, f32 store. C/D: col=lane&15, row=(lane>>4)*4+reg
    const int gn0 = pn * BN + wc * 32;
    float bias[2];
#pragma unroll
    for (int ni = 0; ni < 2; ++ni) bias[ni] = b2[gn0 + ni * 16 + l15];
    const long gm0 = m0 + (long)pm * BM + wr * 128;
#pragma unroll
    for (int mi = 0; mi < 8; ++mi)
#pragma unroll
        for (int ni = 0; ni < 2; ++ni)
#pragma unroll
            for (int j = 0; j < 4; ++j) {
                const long row = gm0 + mi * 16 + l4 * 4 + j;
                out[row * EMBED + gn0 + ni * 16 + l15] = acc[mi][ni][j] + bias[ni];
            }
}

extern "C" void kernel_launch(void* const* d_in, const int* in_sizes, int n_in,
                              void* d_out, int out_size, void* d_ws, size_t ws_size,
                              hipStream_t stream)
{
    const float* x     = (const float*)d_in[0];
    const float* theta = (const float*)d_in[1];
    const float* W1    = (const float*)d_in[2];
    const float* b1    = (const float*)d_in[3];
    const float* W2    = (const float*)d_in[4];
    const float* b2    = (const float*)d_in[5];
    float* out = (float*)d_out;

    const size_t w2b = (size_t)EMBED * FFN * 2;          // 8.4 MB bf16 W2
    __hip_bfloat16* Bw = (__hip_bfloat16*)d_ws;
    __hip_bfloat16* h  = (__hip_bfloat16*)((char*)d_ws + w2b);
    const size_t avail = ws_size > w2b ? ws_size - w2b : 0;

    long chunk = (long)((avail / ((size_t)FFN * 2)) & ~2047UL); // mult of 2048 rows
    if (chunk > MTOT) chunk = MTOT;
    if (chunk < 2048) chunk = 2048;

    cvtW2_kernel<<<(EMBED * FFN) / 2048, 256, 0, stream>>>(W2, Bw);

    for (long m0 = 0; m0 < MTOT; m0 += chunk) {
        const long rows = (MTOT - m0 < chunk) ? (MTOT - m0) : chunk;
        hprod2_kernel<<<(int)((rows / STRIP) * 2), 256, 0, stream>>>(
            x, theta, W1, b1, h, (int)m0);
        const int nPm = (int)(rows / BM);                 // multiple of 8
        gemm4_kernel<<<nPm * 8, 512, 0, stream>>>(h, Bw, b2, out, m0, nPm);
    }
}

// Round 5
// 491.544 us; speedup vs baseline: 1.2101x; 1.2101x over previous
//
#include <hip/hip_runtime.h>
#include <hip/hip_bf16.h>
#include <math.h>

#define EMBED 1024
#define FFN   4096
#define NW    8
#define MTOT  32768   // 16*2048

#define BM 64
#define BN 512
#define BK 64
#define NT (FFN / BK)   // 64 K-tiles

#define STRIP 128
#define KPT   8

typedef __attribute__((ext_vector_type(8))) short          short8v;
typedef __attribute__((ext_vector_type(8))) unsigned short ushort8v;
typedef __attribute__((ext_vector_type(4))) float          f32x4;

typedef __attribute__((address_space(1))) void gvoid_t;
typedef __attribute__((address_space(3))) void svoid_t;

#define VMCNT(n)  asm volatile("s_waitcnt vmcnt(" #n ")" ::: "memory")
#define SCHEDB()  __builtin_amdgcn_sched_barrier(0)
#define BAR()     __builtin_amdgcn_s_barrier()

static __device__ __forceinline__ unsigned short bf16bits(float f) {
    __hip_bfloat16 h = __float2bfloat16(f);
    return *reinterpret_cast<unsigned short*>(&h);
}

// ---------------- W2 f32 -> bf16 (once, into ws) ----------------
__global__ __launch_bounds__(256) void cvtW2_kernel(const float* __restrict__ W2,
                                                    __hip_bfloat16* __restrict__ Bw) {
    const long i0 = ((long)blockIdx.x * 256 + threadIdx.x) * 8;
    const float4 a = *(const float4*)(W2 + i0);
    const float4 b = *(const float4*)(W2 + i0 + 4);
    float fs[8] = {a.x, a.y, a.z, a.w, b.x, b.y, b.z, b.w};
    ushort8v v;
#pragma unroll
    for (int t = 0; t < 8; ++t) v[t] = bf16bits(fs[t]);
    *reinterpret_cast<ushort8v*>(Bw + i0) = v;
}

// ---------------- producer: h[m,k] = relu(b1[k] + qz[m,:]·W1[k,:]) ----------------
__global__ __launch_bounds__(256) void hprod2_kernel(
    const float* __restrict__ x, const float* __restrict__ theta,
    const float* __restrict__ W1, const float* __restrict__ b1,
    __hip_bfloat16* __restrict__ h, int m0)
{
    __shared__ float qz_lds[STRIP][NW];
    const int tid   = threadIdx.x;
    const int khalf = blockIdx.x & 1;
    const int strip = blockIdx.x >> 1;
    const int k0    = khalf * 2048 + tid * KPT;

    float w1r[KPT][NW];
    float b1r[KPT];
#pragma unroll
    for (int i = 0; i < KPT; ++i) {
        const float4 a = *(const float4*)(W1 + (long)(k0 + i) * NW);
        const float4 b = *(const float4*)(W1 + (long)(k0 + i) * NW + 4);
        w1r[i][0] = a.x; w1r[i][1] = a.y; w1r[i][2] = a.z; w1r[i][3] = a.w;
        w1r[i][4] = b.x; w1r[i][5] = b.y; w1r[i][6] = b.z; w1r[i][7] = b.w;
        b1r[i] = b1[k0 + i];
    }

    if (tid < STRIP) {
        const long m = (long)m0 + (long)strip * STRIP + tid;
        const float* xr = x + m * (long)EMBED;
#pragma unroll
        for (int w = 0; w < NW; ++w)
            qz_lds[tid][w] = cosf(xr[w]) * cosf(theta[w]);
    }
    __syncthreads();

    __hip_bfloat16* hp = h + ((long)strip * STRIP) * FFN + k0;
    for (int r = 0; r < STRIP; ++r) {
        float q[NW];
#pragma unroll
        for (int w = 0; w < NW; ++w) q[w] = qz_lds[r][w];
        ushort8v hv;
#pragma unroll
        for (int i = 0; i < KPT; ++i) {
            float acc = b1r[i];
#pragma unroll
            for (int w = 0; w < NW; ++w) acc = fmaf(q[w], w1r[i][w], acc);
            hv[i] = bf16bits(fmaxf(acc, 0.0f));
        }
        *reinterpret_cast<ushort8v*>(hp + (long)r * FFN) = hv;
    }
}

// ---------------- GEMM v5: A-traffic-minimizing wide-N tile ----------------
// out[M,1024] = h[M,4096] @ W2bf[1024,4096]^T + b2
// Diagnosis R4: kernel is A-feed-bound through L3 (~3.7 TB/s); traffic =
// (1024/BN) * 268MB. BN=512 cuts re-read 8x -> 2x (536MB ~ 145us).
// BM=64 BN=512 BK=64; 8 waves; wave owns 64x512/8 = 64x64 (4mi x 4ni x 2kk
// = 32 MFMA/tile). LDS: A 3-deep (24KB) + B 2-deep (128KB) = 152KB, 1 blk/CU.
// Per iter t: vmcnt -> barrier -> issue B(t+1)[8 loads] + A(t+2)[1 load]
//   -> ds_read tile t -> 32 MFMA. FIFO: at top of iter t outstanding =
//   B(t)[8] + A(t+1)[1]; vmcnt(1) drains B(t)+A(t-...) keeping A(t+1) in
//   flight => A-stream (the L3-bound one) never drains; B is L2-resident and
//   1-wall-old (>= 1300cy) at its drain => free. Never vmcnt(0) until tail.
// XCD map: pn = xcd&1 (B-panel 4MB stays L2-hot per XCD), pm streamed once.
// Swizzle: R4-proven zero-conflict pair (pre-swizzled global source
// col ^ (row&7), swizzled ds_read col) on both A and B.
__global__ __launch_bounds__(512, 2) void gemm5_kernel(
    const __hip_bfloat16* __restrict__ A,   // [rows][FFN] chunk-local h
    const __hip_bfloat16* __restrict__ Bw,  // [EMBED][FFN] W2 bf16
    const float* __restrict__ b2,
    float* __restrict__ out, long m0, int nPm)
{
    __shared__ __align__(16) __hip_bfloat16 As[3][BM * BK];  // 24 KB
    __shared__ __align__(16) __hip_bfloat16 Bs[2][BN * BK];  // 128 KB

    const int tid = threadIdx.x, wid = tid >> 6, lane = tid & 63;
    const int l15 = lane & 15, l4 = lane >> 4;

    const int xcd  = blockIdx.x & 7, slot = blockIdx.x >> 3;
    const int pn   = xcd & 1;                       // B-panel per XCD parity
    const int pm   = (xcd >> 1) * (nPm >> 2) + slot;

    // staging: 8 lanes/row (128B rows), row within 8-row sweep = lane>>3;
    // source col pre-swizzled so linear LDS + XOR read is conflict-free (R4)
    const int sr    = lane >> 3;
    const int colsw = ((lane & 7) ^ sr) * 8;

    const __hip_bfloat16* Ag  = A  + (long)(pm * BM + wid * 8 + sr) * FFN + colsw;
    const __hip_bfloat16* Bg0 = Bw + (long)(pn * BN + wid * 8 + sr) * FFN + colsw;

    f32x4 acc[4][4];
#pragma unroll
    for (int i = 0; i < 4; ++i)
#pragma unroll
        for (int j = 0; j < 4; ++j) acc[i][j] = (f32x4){0.f, 0.f, 0.f, 0.f};

#define STAGE_A5(t) do {                                                        \
    __builtin_amdgcn_global_load_lds((gvoid_t*)(Ag + (t) * BK),                 \
        (svoid_t*)(&As[(t) % 3][(wid * 8) * BK]), 16, 0, 0);                    \
} while (0)

#define STAGE_B5(t) do {                                                        \
    _Pragma("unroll")                                                           \
    for (int _j = 0; _j < 8; ++_j)                                              \
        __builtin_amdgcn_global_load_lds(                                       \
            (gvoid_t*)(Bg0 + (long)_j * 64 * FFN + (t) * BK),                   \
            (svoid_t*)(&Bs[(t) & 1][(_j * 64 + wid * 8) * BK]), 16, 0, 0);      \
} while (0)

    // prologue in steady-state FIFO order
    STAGE_A5(0); STAGE_B5(0); STAGE_A5(1);

    const int rx = (l15 & 7) << 3;   // read-side XOR (row&7)<<3 in elems

    for (int t = 0; t < NT; ++t) {
        if (t < NT - 1) { VMCNT(1); } else { VMCNT(0); }
        SCHEDB(); BAR(); SCHEDB();          // tile t resident for all waves

        if (t + 1 < NT) STAGE_B5(t + 1);
        if (t + 2 < NT) STAGE_A5(t + 2);
        SCHEDB();                           // keep feed ahead of reads/MFMA

        const __hip_bfloat16* as = As[t % 3];
        const __hip_bfloat16* bs = Bs[t & 1];

        short8v av[4][2], bv[4][2];
#pragma unroll
        for (int ni = 0; ni < 4; ++ni)
#pragma unroll
            for (int kk = 0; kk < 2; ++kk) {
                const int row = wid * 64 + ni * 16 + l15;
                bv[ni][kk] = *reinterpret_cast<const short8v*>(
                    &bs[row * BK + ((kk * 32 + l4 * 8) ^ rx)]);
            }
#pragma unroll
        for (int mi = 0; mi < 4; ++mi)
#pragma unroll
            for (int kk = 0; kk < 2; ++kk) {
                const int row = mi * 16 + l15;
                av[mi][kk] = *reinterpret_cast<const short8v*>(
                    &as[row * BK + ((kk * 32 + l4 * 8) ^ rx)]);
            }

        __builtin_amdgcn_s_setprio(1);
#pragma unroll
        for (int mi = 0; mi < 4; ++mi)
#pragma unroll
            for (int ni = 0; ni < 4; ++ni)
#pragma unroll
                for (int kk = 0; kk < 2; ++kk)
                    acc[mi][ni] = __builtin_amdgcn_mfma_f32_16x16x32_bf16(
                        av[mi][kk], bv[ni][kk], acc[mi][ni], 0, 0, 0);
        __builtin_amdgcn_s_setprio(0);
    }

#undef STAGE_A5
#undef STAGE_B5

    // epilogue: + b2, f32 store. C/D: col=lane&15, row=(lane>>4)*4+reg
    const int gn0 = pn * BN + wid * 64;
    float bias[4];
#pragma unroll
    for (int ni = 0; ni < 4; ++ni) bias[ni] = b2[gn0 + ni * 16 + l15];
    const long gm0 = m0 + (long)pm * BM;
#pragma unroll
    for (int mi = 0; mi < 4; ++mi)
#pragma unroll
        for (int ni = 0; ni < 4; ++ni)
#pragma unroll
            for (int j = 0; j < 4; ++j) {
                const long row = gm0 + mi * 16 + l4 * 4 + j;
                out[row * EMBED + gn0 + ni * 16 + l15] = acc[mi][ni][j] + bias[ni];
            }
}

extern "C" void kernel_launch(void* const* d_in, const int* in_sizes, int n_in,
                              void* d_out, int out_size, void* d_ws, size_t ws_size,
                              hipStream_t stream)
{
    const float* x     = (const float*)d_in[0];
    const float* theta = (const float*)d_in[1];
    const float* W1    = (const float*)d_in[2];
    const float* b1    = (const float*)d_in[3];
    const float* W2    = (const float*)d_in[4];
    const float* b2    = (const float*)d_in[5];
    float* out = (float*)d_out;

    const size_t w2b = (size_t)EMBED * FFN * 2;          // 8.4 MB bf16 W2
    __hip_bfloat16* Bw = (__hip_bfloat16*)d_ws;
    __hip_bfloat16* h  = (__hip_bfloat16*)((char*)d_ws + w2b);
    const size_t avail = ws_size > w2b ? ws_size - w2b : 0;

    long chunk = (long)((avail / ((size_t)FFN * 2)) & ~2047UL); // mult of 2048 rows
    if (chunk > MTOT) chunk = MTOT;
    if (chunk < 2048) chunk = 2048;

    cvtW2_kernel<<<(EMBED * FFN) / 2048, 256, 0, stream>>>(W2, Bw);

    for (long m0 = 0; m0 < MTOT; m0 += chunk) {
        const long rows = (MTOT - m0 < chunk) ? (MTOT - m0) : chunk;
        hprod2_kernel<<<(int)((rows / STRIP) * 2), 256, 0, stream>>>(
            x, theta, W1, b1, h, (int)m0);
        const int nPm = (int)(rows / BM);                 // multiple of 32
        gemm5_kernel<<<nPm * 2, 512, 0, stream>>>(h, Bw, b2, out, m0, nPm);
    }
}

// Round 7
// 427.253 us; speedup vs baseline: 1.3922x; 1.1505x over previous
//
#include <hip/hip_runtime.h>
#include <hip/hip_bf16.h>
#include <math.h>

#define EMBED 1024
#define FFN   4096
#define NW    8
#define MTOT  32768   // 16*2048

#define BM 256
#define BN 256
#define BK 64
#define NT (FFN / BK)   // 64 K-tiles

#define STRIP 128
#define KPT   8

typedef __attribute__((ext_vector_type(8))) short          short8v;
typedef __attribute__((ext_vector_type(8))) unsigned short ushort8v;
typedef __attribute__((ext_vector_type(4))) float          f32x4;

typedef __attribute__((address_space(1))) void gvoid_t;
typedef __attribute__((address_space(3))) void svoid_t;

#define VMCNT(n)  asm volatile("s_waitcnt vmcnt(" #n ")" ::: "memory")
#define SCHEDB()  __builtin_amdgcn_sched_barrier(0)
#define BAR()     __builtin_amdgcn_s_barrier()

static __device__ __forceinline__ unsigned short bf16bits(float f) {
    __hip_bfloat16 h = __float2bfloat16(f);
    return *reinterpret_cast<unsigned short*>(&h);
}

// ---------------- W2 f32 -> bf16 (once, into ws) ----------------
__global__ __launch_bounds__(256) void cvtW2_kernel(const float* __restrict__ W2,
                                                    __hip_bfloat16* __restrict__ Bw) {
    const long i0 = ((long)blockIdx.x * 256 + threadIdx.x) * 8;
    const float4 a = *(const float4*)(W2 + i0);
    const float4 b = *(const float4*)(W2 + i0 + 4);
    float fs[8] = {a.x, a.y, a.z, a.w, b.x, b.y, b.z, b.w};
    ushort8v v;
#pragma unroll
    for (int t = 0; t < 8; ++t) v[t] = bf16bits(fs[t]);
    *reinterpret_cast<ushort8v*>(Bw + i0) = v;
}

// ---------------- producer: h[m,k] = relu(b1[k] + qz[m,:]·W1[k,:]) ----------------
__global__ __launch_bounds__(256) void hprod2_kernel(
    const float* __restrict__ x, const float* __restrict__ theta,
    const float* __restrict__ W1, const float* __restrict__ b1,
    __hip_bfloat16* __restrict__ h, int m0)
{
    __shared__ float qz_lds[STRIP][NW];
    const int tid   = threadIdx.x;
    const int khalf = blockIdx.x & 1;
    const int strip = blockIdx.x >> 1;
    const int k0    = khalf * 2048 + tid * KPT;

    float w1r[KPT][NW];
    float b1r[KPT];
#pragma unroll
    for (int i = 0; i < KPT; ++i) {
        const float4 a = *(const float4*)(W1 + (long)(k0 + i) * NW);
        const float4 b = *(const float4*)(W1 + (long)(k0 + i) * NW + 4);
        w1r[i][0] = a.x; w1r[i][1] = a.y; w1r[i][2] = a.z; w1r[i][3] = a.w;
        w1r[i][4] = b.x; w1r[i][5] = b.y; w1r[i][6] = b.z; w1r[i][7] = b.w;
        b1r[i] = b1[k0 + i];
    }

    if (tid < STRIP) {
        const long m = (long)m0 + (long)strip * STRIP + tid;
        const float* xr = x + m * (long)EMBED;
#pragma unroll
        for (int w = 0; w < NW; ++w)
            qz_lds[tid][w] = cosf(xr[w]) * cosf(theta[w]);
    }
    __syncthreads();

    __hip_bfloat16* hp = h + ((long)strip * STRIP) * FFN + k0;
    for (int r = 0; r < STRIP; ++r) {
        float q[NW];
#pragma unroll
        for (int w = 0; w < NW; ++w) q[w] = qz_lds[r][w];
        ushort8v hv;
#pragma unroll
        for (int i = 0; i < KPT; ++i) {
            float acc = b1r[i];
#pragma unroll
            for (int w = 0; w < NW; ++w) acc = fmaf(q[w], w1r[i][w], acc);
            hv[i] = bf16bits(fmaxf(acc, 0.0f));
        }
        *reinterpret_cast<ushort8v*>(hp + (long)r * FFN) = hv;
    }
}

// ---------------- GEMM v7: v6 + tail-wait fix ----------------
// out[M,1024] = h[M,4096] @ W2bf[1024,4096]^T + b2
// Identical schedule to v6 (4 phases/K-tile, T3+T4+T5+T2). R6 bug: at iter
// NT-2, P4 stages nothing, so its trailing VMCNT(2) left B(NT-1)h1 in
// flight while iter NT-1's P2 read it -> replay-timing race. Fix: the last
// TWO iterations drain with VMCNT(0) (tail is outside steady state; the
// counted-wait invariant "vmcnt(2) => tile t+1 resident" only holds when
// P4 issued a stage).
// Steady-state ledger (unchanged, proven): at P4-end outstanding =
// {A(t+1)h1, B(t+1)h0, B(t+1)h1, A(t+2)h0} = 8 loads; vmcnt(2) leaves only
// A(t+2)h0 => tile t+1 resident. Overwrite-safety per region verified
// (stage of region X always >=1 barrier after last ds_read of X's previous
// occupant). Swizzle: R4/R5-proven zero-conflict pair.
__global__ __launch_bounds__(512, 2) void gemm7_kernel(
    const __hip_bfloat16* __restrict__ A,   // [rows][FFN] chunk-local h
    const __hip_bfloat16* __restrict__ Bw,  // [EMBED][FFN] W2 bf16
    const float* __restrict__ b2,
    float* __restrict__ out, long m0, int nPm)
{
    __shared__ __align__(16) __hip_bfloat16 As[2][BM * BK];  // 64 KB
    __shared__ __align__(16) __hip_bfloat16 Bs[2][BN * BK];  // 64 KB

    const int tid = threadIdx.x, wid = tid >> 6, lane = tid & 63;
    const int l15 = lane & 15, l4 = lane >> 4;
    const int wr = wid >> 2, wc = wid & 3;           // 2M x 4N wave grid

    // XCD map: all 4 pn of a pm co-resident on one XCD; pm chunked per XCD.
    const int xcd = blockIdx.x & 7, kb = blockIdx.x >> 3;
    const int pn  = kb & 3;
    const int pm  = xcd * (nPm >> 3) + (kb >> 2);

    // staging: thread -> row (tid>>3), 16B slot (tid&7); source col pre-XORed
    // by row&7 so linear LDS + XOR'd ds_read is conflict-free (R4/R5: 0 conf)
    const int srow  = tid >> 3;
    const int colsw = ((tid & 7) ^ (srow & 7)) * 8;

    const __hip_bfloat16* Ag = A  + (long)(pm * BM + srow) * FFN + colsw;
    const __hip_bfloat16* Bg = Bw + (long)(pn * BN + srow) * FFN + colsw;

    f32x4 acc[8][4];
#pragma unroll
    for (int i = 0; i < 8; ++i)
#pragma unroll
        for (int j = 0; j < 4; ++j) acc[i][j] = (f32x4){0.f, 0.f, 0.f, 0.f};

    // half-tile stage: 128 rows x 64 cols, 2 sweeps of 64 rows, 2 loads/thread
#define STAGE_A6(t, h) do {                                                     \
    __hip_bfloat16* _s = &As[(t) & 1][((h) * 128 + wid * 8) * BK];              \
    const __hip_bfloat16* _g = Ag + (long)((h) * 128) * FFN + (t) * BK;         \
    __builtin_amdgcn_global_load_lds((gvoid_t*)_g, (svoid_t*)_s, 16, 0, 0);     \
    __builtin_amdgcn_global_load_lds((gvoid_t*)(_g + (long)64 * FFN),           \
                                     (svoid_t*)(_s + 64 * BK), 16, 0, 0);       \
} while (0)

#define STAGE_B6(t, h) do {                                                     \
    __hip_bfloat16* _s = &Bs[(t) & 1][((h) * 128 + wid * 8) * BK];              \
    const __hip_bfloat16* _g = Bg + (long)((h) * 128) * FFN + (t) * BK;         \
    __builtin_amdgcn_global_load_lds((gvoid_t*)_g, (svoid_t*)_s, 16, 0, 0);     \
    __builtin_amdgcn_global_load_lds((gvoid_t*)(_g + (long)64 * FFN),           \
                                     (svoid_t*)(_s + 64 * BK), 16, 0, 0);       \
} while (0)

    const int rx = (l15 & 7) << 3;   // read-side elem XOR; row&7 == l15&7

    short8v aF[4][2];       // current A half-frags (overwritten P3)
    short8v bF[2][2][2];    // [b-half][ni][kk]; bF[0] lives P1->P4

#define READ_A6(t, a) do { _Pragma("unroll")                                    \
    for (int mi = 0; mi < 4; ++mi) {                                            \
        const int row = wr * 128 + (a) * 64 + mi * 16 + l15;                    \
        _Pragma("unroll") for (int kk = 0; kk < 2; ++kk)                        \
            aF[mi][kk] = *reinterpret_cast<const short8v*>(                     \
                &As[(t) & 1][row * BK + ((kk * 32 + l4 * 8) ^ rx)]);            \
    } } while (0)

#define READ_B6(t, b) do { _Pragma("unroll")                                    \
    for (int ni = 0; ni < 2; ++ni) {                                            \
        const int row = wc * 64 + (b) * 32 + ni * 16 + l15;                     \
        _Pragma("unroll") for (int kk = 0; kk < 2; ++kk)                        \
            bF[b][ni][kk] = *reinterpret_cast<const short8v*>(                  \
                &Bs[(t) & 1][row * BK + ((kk * 32 + l4 * 8) ^ rx)]);            \
    } } while (0)

#define MFMA_Q(aa, bb) do { _Pragma("unroll")                                   \
    for (int mi = 0; mi < 4; ++mi) _Pragma("unroll")                            \
    for (int ni = 0; ni < 2; ++ni) _Pragma("unroll")                            \
    for (int kk = 0; kk < 2; ++kk)                                              \
        acc[(aa) * 4 + mi][(bb) * 2 + ni] =                                     \
            __builtin_amdgcn_mfma_f32_16x16x32_bf16(                            \
                aF[mi][kk], bF[bb][ni][kk], acc[(aa) * 4 + mi][(bb) * 2 + ni],  \
                0, 0, 0);                                                       \
} while (0)

    // prologue: tile0 all 4 halves + A(1)h0 (steady-state FIFO position)
    STAGE_A6(0, 0); STAGE_A6(0, 1); STAGE_B6(0, 0); STAGE_B6(0, 1);
    STAGE_A6(1, 0);
    VMCNT(2); SCHEDB(); BAR(); SCHEDB();

    for (int t = 0; t < NT; ++t) {
        // ---- P1: q(0,0) ----
        if (t + 1 < NT) STAGE_A6(t + 1, 1);
        READ_A6(t, 0); READ_B6(t, 0);
        SCHEDB(); BAR(); SCHEDB();
        __builtin_amdgcn_s_setprio(1); MFMA_Q(0, 0); __builtin_amdgcn_s_setprio(0);
        SCHEDB(); BAR(); SCHEDB();
        // ---- P2: q(0,1) ----
        if (t + 1 < NT) STAGE_B6(t + 1, 0);
        READ_B6(t, 1);
        SCHEDB(); BAR(); SCHEDB();
        __builtin_amdgcn_s_setprio(1); MFMA_Q(0, 1); __builtin_amdgcn_s_setprio(0);
        SCHEDB(); BAR(); SCHEDB();
        // ---- P3: q(1,1) ----
        if (t + 1 < NT) STAGE_B6(t + 1, 1);
        READ_A6(t, 1);
        SCHEDB(); BAR(); SCHEDB();
        __builtin_amdgcn_s_setprio(1); MFMA_Q(1, 1); __builtin_amdgcn_s_setprio(0);
        SCHEDB(); BAR(); SCHEDB();
        // ---- P4: q(1,0), regs only ----
        if (t + 2 < NT) STAGE_A6(t + 2, 0);
        SCHEDB(); BAR(); SCHEDB();
        __builtin_amdgcn_s_setprio(1); MFMA_Q(1, 0); __builtin_amdgcn_s_setprio(0);
        // TAIL FIX (R6 race): steady-state vmcnt(2) is only valid while P4
        // staged A(t+2)h0. For t >= NT-2 the FIFO is under-full -> drain.
        if (t < NT - 2) { VMCNT(2); } else { VMCNT(0); }
        SCHEDB(); BAR(); SCHEDB();
    }

#undef STAGE_A6
#undef STAGE_B6
#undef READ_A6
#undef READ_B6
#undef MFMA_Q

    // epilogue: + b2, f32 store. C/D: col=lane&15, row=(lane>>4)*4+reg
    const int gn0 = pn * BN + wc * 64;
    float bias[4];
#pragma unroll
    for (int ni = 0; ni < 4; ++ni) bias[ni] = b2[gn0 + ni * 16 + l15];
    const long gm0 = m0 + (long)pm * BM + wr * 128;
#pragma unroll
    for (int mi = 0; mi < 8; ++mi)
#pragma unroll
        for (int ni = 0; ni < 4; ++ni)
#pragma unroll
            for (int j = 0; j < 4; ++j) {
                const long row = gm0 + mi * 16 + l4 * 4 + j;
                out[row * EMBED + gn0 + ni * 16 + l15] = acc[mi][ni][j] + bias[ni];
            }
}

extern "C" void kernel_launch(void* const* d_in, const int* in_sizes, int n_in,
                              void* d_out, int out_size, void* d_ws, size_t ws_size,
                              hipStream_t stream)
{
    const float* x     = (const float*)d_in[0];
    const float* theta = (const float*)d_in[1];
    const float* W1    = (const float*)d_in[2];
    const float* b1    = (const float*)d_in[3];
    const float* W2    = (const float*)d_in[4];
    const float* b2    = (const float*)d_in[5];
    float* out = (float*)d_out;

    const size_t w2b = (size_t)EMBED * FFN * 2;          // 8.4 MB bf16 W2
    __hip_bfloat16* Bw = (__hip_bfloat16*)d_ws;
    __hip_bfloat16* h  = (__hip_bfloat16*)((char*)d_ws + w2b);
    const size_t avail = ws_size > w2b ? ws_size - w2b : 0;

    long chunk = (long)((avail / ((size_t)FFN * 2)) & ~2047UL); // mult of 2048 rows
    if (chunk > MTOT) chunk = MTOT;
    if (chunk < 2048) chunk = 2048;

    cvtW2_kernel<<<(EMBED * FFN) / 2048, 256, 0, stream>>>(W2, Bw);

    for (long m0 = 0; m0 < MTOT; m0 += chunk) {
        const long rows = (MTOT - m0 < chunk) ? (MTOT - m0) : chunk;
        hprod2_kernel<<<(int)((rows / STRIP) * 2), 256, 0, stream>>>(
            x, theta, W1, b1, h, (int)m0);
        const int nPm = (int)(rows / BM);                 // multiple of 8
        gemm7_kernel<<<nPm * 4, 512, 0, stream>>>(h, Bw, b2, out, m0, nPm);
    }
}

// Round 8
// 426.792 us; speedup vs baseline: 1.3937x; 1.0011x over previous
//
#include <hip/hip_runtime.h>
#include <hip/hip_bf16.h>
#include <math.h>

#define EMBED 1024
#define FFN   4096
#define NW    8
#define MTOT  32768   // 16*2048

#define BM 256
#define BN 256
#define BK 64
#define NT (FFN / BK)   // 64 K-tiles

#define STRIP 128
#define KPT   8

typedef __attribute__((ext_vector_type(8))) short          short8v;
typedef __attribute__((ext_vector_type(8))) unsigned short ushort8v;
typedef __attribute__((ext_vector_type(4))) float          f32x4;

typedef __attribute__((address_space(1))) void gvoid_t;
typedef __attribute__((address_space(3))) void svoid_t;

// "memory" clobber = full compiler memory fence: no memory op (ds_read,
// global_load_lds issue, store) may cross. This is the ONLY ordering pin we
// keep -- R7's blanket sched_barrier(0)s (24/K-tile) were m141's measured
// failure mode (order-pinning defeats the scheduler) and are removed.
#define VMCNT(n)  asm volatile("s_waitcnt vmcnt(" #n ")" ::: "memory")
#define BAR()     __builtin_amdgcn_s_barrier()

static __device__ __forceinline__ unsigned short bf16bits(float f) {
    __hip_bfloat16 h = __float2bfloat16(f);
    return *reinterpret_cast<unsigned short*>(&h);
}

// ---------------- W2 f32 -> bf16 (once, into ws) ----------------
__global__ __launch_bounds__(256) void cvtW2_kernel(const float* __restrict__ W2,
                                                    __hip_bfloat16* __restrict__ Bw) {
    const long i0 = ((long)blockIdx.x * 256 + threadIdx.x) * 8;
    const float4 a = *(const float4*)(W2 + i0);
    const float4 b = *(const float4*)(W2 + i0 + 4);
    float fs[8] = {a.x, a.y, a.z, a.w, b.x, b.y, b.z, b.w};
    ushort8v v;
#pragma unroll
    for (int t = 0; t < 8; ++t) v[t] = bf16bits(fs[t]);
    *reinterpret_cast<ushort8v*>(Bw + i0) = v;
}

// ---------------- producer: h[m,k] = relu(b1[k] + qz[m,:]·W1[k,:]) ----------------
__global__ __launch_bounds__(256) void hprod2_kernel(
    const float* __restrict__ x, const float* __restrict__ theta,
    const float* __restrict__ W1, const float* __restrict__ b1,
    __hip_bfloat16* __restrict__ h, int m0)
{
    __shared__ float qz_lds[STRIP][NW];
    const int tid   = threadIdx.x;
    const int khalf = blockIdx.x & 1;
    const int strip = blockIdx.x >> 1;
    const int k0    = khalf * 2048 + tid * KPT;

    float w1r[KPT][NW];
    float b1r[KPT];
#pragma unroll
    for (int i = 0; i < KPT; ++i) {
        const float4 a = *(const float4*)(W1 + (long)(k0 + i) * NW);
        const float4 b = *(const float4*)(W1 + (long)(k0 + i) * NW + 4);
        w1r[i][0] = a.x; w1r[i][1] = a.y; w1r[i][2] = a.z; w1r[i][3] = a.w;
        w1r[i][4] = b.x; w1r[i][5] = b.y; w1r[i][6] = b.z; w1r[i][7] = b.w;
        b1r[i] = b1[k0 + i];
    }

    if (tid < STRIP) {
        const long m = (long)m0 + (long)strip * STRIP + tid;
        const float* xr = x + m * (long)EMBED;
#pragma unroll
        for (int w = 0; w < NW; ++w)
            qz_lds[tid][w] = cosf(xr[w]) * cosf(theta[w]);
    }
    __syncthreads();

    __hip_bfloat16* hp = h + ((long)strip * STRIP) * FFN + k0;
    for (int r = 0; r < STRIP; ++r) {
        float q[NW];
#pragma unroll
        for (int w = 0; w < NW; ++w) q[w] = qz_lds[r][w];
        ushort8v hv;
#pragma unroll
        for (int i = 0; i < KPT; ++i) {
            float acc = b1r[i];
#pragma unroll
            for (int w = 0; w < NW; ++w) acc = fmaf(q[w], w1r[i][w], acc);
            hv[i] = bf16bits(fmaxf(acc, 0.0f));
        }
        *reinterpret_cast<ushort8v*>(hp + (long)r * FFN) = hv;
    }
}

// ---------------- GEMM v8: v7 minus sched_barrier order-pinning ----------------
// Identical sync structure to v7 (proven correct): 4 phases/K-tile, dbuf LDS,
// one counted vmcnt(2)/tile (tail: vmcnt(0) last two iters), zero-conflict
// XOR swizzle, setprio around MFMA clusters.
// ONLY change: all __builtin_amdgcn_sched_barrier(0) removed. Correctness
// argument: every buffer-overwrite hazard is separated from its reads by a
// VMCNT whose asm "memory" clobber is a full compiler memory fence (no
// memory op crosses it); within an iteration, reads and stages target
// disjoint double-buffer halves, so reordering across bare s_barriers is
// harmless; MFMA<-ds_read ordering is a register data-dep the compiler
// tracks with its own lgkmcnt. Perf rationale: m141 (order-pinning = 874->
// 510 TF) and m196 (the fine ds_read||stage||MFMA interleave IS the lever).
__global__ __launch_bounds__(512, 2) void gemm8_kernel(
    const __hip_bfloat16* __restrict__ A,   // [rows][FFN] chunk-local h
    const __hip_bfloat16* __restrict__ Bw,  // [EMBED][FFN] W2 bf16
    const float* __restrict__ b2,
    float* __restrict__ out, long m0, int nPm)
{
    __shared__ __align__(16) __hip_bfloat16 As[2][BM * BK];  // 64 KB
    __shared__ __align__(16) __hip_bfloat16 Bs[2][BN * BK];  // 64 KB

    const int tid = threadIdx.x, wid = tid >> 6, lane = tid & 63;
    const int l15 = lane & 15, l4 = lane >> 4;
    const int wr = wid >> 2, wc = wid & 3;           // 2M x 4N wave grid

    // XCD map: all 4 pn of a pm co-resident on one XCD; pm chunked per XCD.
    const int xcd = blockIdx.x & 7, kb = blockIdx.x >> 3;
    const int pn  = kb & 3;
    const int pm  = xcd * (nPm >> 3) + (kb >> 2);

    // staging: thread -> row (tid>>3), 16B slot (tid&7); source col pre-XORed
    // by row&7 so linear LDS + XOR'd ds_read is conflict-free (R4/R5: 0 conf)
    const int srow  = tid >> 3;
    const int colsw = ((tid & 7) ^ (srow & 7)) * 8;

    const __hip_bfloat16* Ag = A  + (long)(pm * BM + srow) * FFN + colsw;
    const __hip_bfloat16* Bg = Bw + (long)(pn * BN + srow) * FFN + colsw;

    f32x4 acc[8][4];
#pragma unroll
    for (int i = 0; i < 8; ++i)
#pragma unroll
        for (int j = 0; j < 4; ++j) acc[i][j] = (f32x4){0.f, 0.f, 0.f, 0.f};

    // half-tile stage: 128 rows x 64 cols, 2 sweeps of 64 rows, 2 loads/thread
#define STAGE_A6(t, h) do {                                                     \
    __hip_bfloat16* _s = &As[(t) & 1][((h) * 128 + wid * 8) * BK];              \
    const __hip_bfloat16* _g = Ag + (long)((h) * 128) * FFN + (t) * BK;         \
    __builtin_amdgcn_global_load_lds((gvoid_t*)_g, (svoid_t*)_s, 16, 0, 0);     \
    __builtin_amdgcn_global_load_lds((gvoid_t*)(_g + (long)64 * FFN),           \
                                     (svoid_t*)(_s + 64 * BK), 16, 0, 0);       \
} while (0)

#define STAGE_B6(t, h) do {                                                     \
    __hip_bfloat16* _s = &Bs[(t) & 1][((h) * 128 + wid * 8) * BK];              \
    const __hip_bfloat16* _g = Bg + (long)((h) * 128) * FFN + (t) * BK;         \
    __builtin_amdgcn_global_load_lds((gvoid_t*)_g, (svoid_t*)_s, 16, 0, 0);     \
    __builtin_amdgcn_global_load_lds((gvoid_t*)(_g + (long)64 * FFN),           \
                                     (svoid_t*)(_s + 64 * BK), 16, 0, 0);       \
} while (0)

    const int rx = (l15 & 7) << 3;   // read-side elem XOR; row&7 == l15&7

    short8v aF[4][2];       // current A half-frags (overwritten P3)
    short8v bF[2][2][2];    // [b-half][ni][kk]; bF[0] lives P1->P4

#define READ_A6(t, a) do { _Pragma("unroll")                                    \
    for (int mi = 0; mi < 4; ++mi) {                                            \
        const int row = wr * 128 + (a) * 64 + mi * 16 + l15;                    \
        _Pragma("unroll") for (int kk = 0; kk < 2; ++kk)                        \
            aF[mi][kk] = *reinterpret_cast<const short8v*>(                     \
                &As[(t) & 1][row * BK + ((kk * 32 + l4 * 8) ^ rx)]);            \
    } } while (0)

#define READ_B6(t, b) do { _Pragma("unroll")                                    \
    for (int ni = 0; ni < 2; ++ni) {                                            \
        const int row = wc * 64 + (b) * 32 + ni * 16 + l15;                     \
        _Pragma("unroll") for (int kk = 0; kk < 2; ++kk)                        \
            bF[b][ni][kk] = *reinterpret_cast<const short8v*>(                  \
                &Bs[(t) & 1][row * BK + ((kk * 32 + l4 * 8) ^ rx)]);            \
    } } while (0)

#define MFMA_Q(aa, bb) do { _Pragma("unroll")                                   \
    for (int mi = 0; mi < 4; ++mi) _Pragma("unroll")                            \
    for (int ni = 0; ni < 2; ++ni) _Pragma("unroll")                            \
    for (int kk = 0; kk < 2; ++kk)                                              \
        acc[(aa) * 4 + mi][(bb) * 2 + ni] =                                     \
            __builtin_amdgcn_mfma_f32_16x16x32_bf16(                            \
                aF[mi][kk], bF[bb][ni][kk], acc[(aa) * 4 + mi][(bb) * 2 + ni],  \
                0, 0, 0);                                                       \
} while (0)

    // prologue: tile0 all 4 halves + A(1)h0 (steady-state FIFO position)
    STAGE_A6(0, 0); STAGE_A6(0, 1); STAGE_B6(0, 0); STAGE_B6(0, 1);
    STAGE_A6(1, 0);
    VMCNT(2); BAR();

    for (int t = 0; t < NT; ++t) {
        // ---- P1: q(0,0) ----
        if (t + 1 < NT) STAGE_A6(t + 1, 1);
        READ_A6(t, 0); READ_B6(t, 0);
        BAR();
        __builtin_amdgcn_s_setprio(1); MFMA_Q(0, 0); __builtin_amdgcn_s_setprio(0);
        BAR();
        // ---- P2: q(0,1) ----
        if (t + 1 < NT) STAGE_B6(t + 1, 0);
        READ_B6(t, 1);
        BAR();
        __builtin_amdgcn_s_setprio(1); MFMA_Q(0, 1); __builtin_amdgcn_s_setprio(0);
        BAR();
        // ---- P3: q(1,1) ----
        if (t + 1 < NT) STAGE_B6(t + 1, 1);
        READ_A6(t, 1);
        BAR();
        __builtin_amdgcn_s_setprio(1); MFMA_Q(1, 1); __builtin_amdgcn_s_setprio(0);
        BAR();
        // ---- P4: q(1,0), regs only ----
        if (t + 2 < NT) STAGE_A6(t + 2, 0);
        BAR();
        __builtin_amdgcn_s_setprio(1); MFMA_Q(1, 0); __builtin_amdgcn_s_setprio(0);
        // TAIL (R6 race fix): steady-state vmcnt(2) only valid while P4
        // staged A(t+2)h0. For t >= NT-2 the FIFO is under-full -> drain.
        if (t < NT - 2) { VMCNT(2); } else { VMCNT(0); }
        BAR();
    }

#undef STAGE_A6
#undef STAGE_B6
#undef READ_A6
#undef READ_B6
#undef MFMA_Q

    // epilogue: + b2, f32 store. C/D: col=lane&15, row=(lane>>4)*4+reg
    const int gn0 = pn * BN + wc * 64;
    float bias[4];
#pragma unroll
    for (int ni = 0; ni < 4; ++ni) bias[ni] = b2[gn0 + ni * 16 + l15];
    const long gm0 = m0 + (long)pm * BM + wr * 128;
#pragma unroll
    for (int mi = 0; mi < 8; ++mi)
#pragma unroll
        for (int ni = 0; ni < 4; ++ni)
#pragma unroll
            for (int j = 0; j < 4; ++j) {
                const long row = gm0 + mi * 16 + l4 * 4 + j;
                out[row * EMBED + gn0 + ni * 16 + l15] = acc[mi][ni][j] + bias[ni];
            }
}

extern "C" void kernel_launch(void* const* d_in, const int* in_sizes, int n_in,
                              void* d_out, int out_size, void* d_ws, size_t ws_size,
                              hipStream_t stream)
{
    const float* x     = (const float*)d_in[0];
    const float* theta = (const float*)d_in[1];
    const float* W1    = (const float*)d_in[2];
    const float* b1    = (const float*)d_in[3];
    const float* W2    = (const float*)d_in[4];
    const float* b2    = (const float*)d_in[5];
    float* out = (float*)d_out;

    const size_t w2b = (size_t)EMBED * FFN * 2;          // 8.4 MB bf16 W2
    __hip_bfloat16* Bw = (__hip_bfloat16*)d_ws;
    __hip_bfloat16* h  = (__hip_bfloat16*)((char*)d_ws + w2b);
    const size_t avail = ws_size > w2b ? ws_size - w2b : 0;

    long chunk = (long)((avail / ((size_t)FFN * 2)) & ~2047UL); // mult of 2048 rows
    if (chunk > MTOT) chunk = MTOT;
    if (chunk < 2048) chunk = 2048;

    cvtW2_kernel<<<(EMBED * FFN) / 2048, 256, 0, stream>>>(W2, Bw);

    for (long m0 = 0; m0 < MTOT; m0 += chunk) {
        const long rows = (MTOT - m0 < chunk) ? (MTOT - m0) : chunk;
        hprod2_kernel<<<(int)((rows / STRIP) * 2), 256, 0, stream>>>(
            x, theta, W1, b1, h, (int)m0);
        const int nPm = (int)(rows / BM);                 // multiple of 8
        gemm8_kernel<<<nPm * 4, 512, 0, stream>>>(h, Bw, b2, out, m0, nPm);
    }
}

// Round 9
// 393.050 us; speedup vs baseline: 1.5133x; 1.0858x over previous
//
#include <hip/hip_runtime.h>
#include <hip/hip_bf16.h>
#include <math.h>

#define EMBED 1024
#define FFN   4096
#define NW    8
#define MTOT  32768   // 16*2048

#define BM 128
#define BN 128
#define BK 64
#define NT (FFN / BK)   // 64 K-tiles

#define STRIP 128
#define KPT   8

typedef __attribute__((ext_vector_type(8))) short          short8v;
typedef __attribute__((ext_vector_type(8))) unsigned short ushort8v;
typedef __attribute__((ext_vector_type(4))) float          f32x4;

typedef __attribute__((address_space(1))) void gvoid_t;
typedef __attribute__((address_space(3))) void svoid_t;

static __device__ __forceinline__ unsigned short bf16bits(float f) {
    __hip_bfloat16 h = __float2bfloat16(f);
    return *reinterpret_cast<unsigned short*>(&h);
}

// ---------------- W2 f32 -> bf16 (once, into ws) ----------------
__global__ __launch_bounds__(256) void cvtW2_kernel(const float* __restrict__ W2,
                                                    __hip_bfloat16* __restrict__ Bw) {
    const long i0 = ((long)blockIdx.x * 256 + threadIdx.x) * 8;
    const float4 a = *(const float4*)(W2 + i0);
    const float4 b = *(const float4*)(W2 + i0 + 4);
    float fs[8] = {a.x, a.y, a.z, a.w, b.x, b.y, b.z, b.w};
    ushort8v v;
#pragma unroll
    for (int t = 0; t < 8; ++t) v[t] = bf16bits(fs[t]);
    *reinterpret_cast<ushort8v*>(Bw + i0) = v;
}

// ---------------- producer: h[m,k] = relu(b1[k] + qz[m,:]·W1[k,:]) ----------------
__global__ __launch_bounds__(256) void hprod2_kernel(
    const float* __restrict__ x, const float* __restrict__ theta,
    const float* __restrict__ W1, const float* __restrict__ b1,
    __hip_bfloat16* __restrict__ h, int m0)
{
    __shared__ float qz_lds[STRIP][NW];
    const int tid   = threadIdx.x;
    const int khalf = blockIdx.x & 1;
    const int strip = blockIdx.x >> 1;
    const int k0    = khalf * 2048 + tid * KPT;

    float w1r[KPT][NW];
    float b1r[KPT];
#pragma unroll
    for (int i = 0; i < KPT; ++i) {
        const float4 a = *(const float4*)(W1 + (long)(k0 + i) * NW);
        const float4 b = *(const float4*)(W1 + (long)(k0 + i) * NW + 4);
        w1r[i][0] = a.x; w1r[i][1] = a.y; w1r[i][2] = a.z; w1r[i][3] = a.w;
        w1r[i][4] = b.x; w1r[i][5] = b.y; w1r[i][6] = b.z; w1r[i][7] = b.w;
        b1r[i] = b1[k0 + i];
    }

    if (tid < STRIP) {
        const long m = (long)m0 + (long)strip * STRIP + tid;
        const float* xr = x + m * (long)EMBED;
#pragma unroll
        for (int w = 0; w < NW; ++w)
            qz_lds[tid][w] = cosf(xr[w]) * cosf(theta[w]);
    }
    __syncthreads();

    __hip_bfloat16* hp = h + ((long)strip * STRIP) * FFN + k0;
    for (int r = 0; r < STRIP; ++r) {
        float q[NW];
#pragma unroll
        for (int w = 0; w < NW; ++w) q[w] = qz_lds[r][w];
        ushort8v hv;
#pragma unroll
        for (int i = 0; i < KPT; ++i) {
            float acc = b1r[i];
#pragma unroll
            for (int w = 0; w < NW; ++w) acc = fmaf(q[w], w1r[i][w], acc);
            hv[i] = bf16bits(fmaxf(acc, 0.0f));
        }
        *reinterpret_cast<ushort8v*>(hp + (long)r * FFN) = hv;
    }
}

// ---------------- GEMM v9: m97-faithful, occupancy-hiding ----------------
// out[M,1024] = h[M,4096] @ W2bf[1024,4096]^T + b2
// R8 accounting: 1-block/CU lockstep => LDS-read (1129cyc) + MFMA (620cyc)
// + barriers ADD per phase (7780 cyc/tile). Fix per m97/m114: INDEPENDENT
// co-resident blocks overlap each other's read/MFMA/barrier intervals.
// 128x128 tile, BK=64, 4 waves (2x2), wave owns 64x64 (acc 64 VGPR).
// LDS = single-buffered As+Bs = 32KB; plain __syncthreads (vmcnt0 drain is
// m97's structure, hidden by ~4 blocks/CU). Zero inline asm.
// Swizzle: proven zero-conflict pair (source col16 ^= row&7; same XOR on read).
// XCD map: xcd owns contiguous pm range; per pm, all 8 pn consecutive ->
// A panel (1MB) L2-hot, B panels (1MB each) cycle.
__global__ __launch_bounds__(256) void gemm9_kernel(
    const __hip_bfloat16* __restrict__ A,   // [rows][FFN] chunk-local h
    const __hip_bfloat16* __restrict__ Bw,  // [EMBED][FFN] W2 bf16
    const float* __restrict__ b2,
    float* __restrict__ out, long m0, int nPm)
{
    __shared__ __align__(16) __hip_bfloat16 As[BM * BK];  // 16 KB
    __shared__ __align__(16) __hip_bfloat16 Bs[BN * BK];  // 16 KB

    const int tid = threadIdx.x, wid = tid >> 6, lane = tid & 63;
    const int l15 = lane & 15, l4 = lane >> 4;
    const int wr = wid >> 1, wc = wid & 1;          // 2M x 2N wave grid

    // XCD map: bid = xcd + 8*j; same-xcd bids are j-consecutive.
    // j = (pmLocal<<3) | pn  -> per pm, 8 pn back-to-back on one XCD.
    const int xcd = blockIdx.x & 7, j = blockIdx.x >> 3;
    const int pn  = j & 7;
    const int pm  = xcd * (nPm >> 3) + (j >> 3);

    // staging: 8 threads/row (8x16B = 128B row); 4 sweeps of 32 rows.
    // Global source col pre-XORed by row&7 -> linear LDS + XOR'd read = 0 conf.
    const int srow  = tid >> 3;                     // 0..31
    const int colsw = ((tid & 7) ^ (srow & 7)) * 8;

    const __hip_bfloat16* Ag = A  + (long)(pm * BM + srow) * FFN + colsw;
    const __hip_bfloat16* Bg = Bw + (long)(pn * BN + srow) * FFN + colsw;

    f32x4 acc[4][4];
#pragma unroll
    for (int i = 0; i < 4; ++i)
#pragma unroll
        for (int jj = 0; jj < 4; ++jj) acc[i][jj] = (f32x4){0.f, 0.f, 0.f, 0.f};

    const int rx = (l15 & 7) << 3;   // read-side elem XOR; row&7 == l15&7

    for (int t = 0; t < NT; ++t) {
        __syncthreads();   // previous tile's reads complete before overwrite
        // stage A,B: 4 sweeps x (1 A + 1 B) gload_lds per thread
#pragma unroll
        for (int s = 0; s < 4; ++s) {
            __builtin_amdgcn_global_load_lds(
                (gvoid_t*)(Ag + (long)(s * 32) * FFN + t * BK),
                (svoid_t*)(&As[(s * 32 + wid * 8) * BK]), 16, 0, 0);
            __builtin_amdgcn_global_load_lds(
                (gvoid_t*)(Bg + (long)(s * 32) * FFN + t * BK),
                (svoid_t*)(&Bs[(s * 32 + wid * 8) * BK]), 16, 0, 0);
        }
        __syncthreads();   // emits vmcnt(0) drain (m97 structure; blocks/CU hide)

        short8v av[4][2], bv[4][2];
#pragma unroll
        for (int mi = 0; mi < 4; ++mi)
#pragma unroll
            for (int kk = 0; kk < 2; ++kk) {
                const int row = wr * 64 + mi * 16 + l15;
                av[mi][kk] = *reinterpret_cast<const short8v*>(
                    &As[row * BK + ((kk * 32 + l4 * 8) ^ rx)]);
            }
#pragma unroll
        for (int ni = 0; ni < 4; ++ni)
#pragma unroll
            for (int kk = 0; kk < 2; ++kk) {
                const int row = wc * 64 + ni * 16 + l15;
                bv[ni][kk] = *reinterpret_cast<const short8v*>(
                    &Bs[row * BK + ((kk * 32 + l4 * 8) ^ rx)]);
            }
#pragma unroll
        for (int mi = 0; mi < 4; ++mi)
#pragma unroll
            for (int ni = 0; ni < 4; ++ni)
#pragma unroll
                for (int kk = 0; kk < 2; ++kk)
                    acc[mi][ni] = __builtin_amdgcn_mfma_f32_16x16x32_bf16(
                        av[mi][kk], bv[ni][kk], acc[mi][ni], 0, 0, 0);
    }

    // epilogue: + b2, f32 store. C/D: col=lane&15, row=(lane>>4)*4+reg
    const int gn0 = pn * BN + wc * 64;
    float bias[4];
#pragma unroll
    for (int ni = 0; ni < 4; ++ni) bias[ni] = b2[gn0 + ni * 16 + l15];
    const long gm0 = m0 + (long)pm * BM + wr * 64;
#pragma unroll
    for (int mi = 0; mi < 4; ++mi)
#pragma unroll
        for (int ni = 0; ni < 4; ++ni)
#pragma unroll
            for (int jj = 0; jj < 4; ++jj) {
                const long row = gm0 + mi * 16 + l4 * 4 + jj;
                out[row * EMBED + gn0 + ni * 16 + l15] = acc[mi][ni][jj] + bias[ni];
            }
}

extern "C" void kernel_launch(void* const* d_in, const int* in_sizes, int n_in,
                              void* d_out, int out_size, void* d_ws, size_t ws_size,
                              hipStream_t stream)
{
    const float* x     = (const float*)d_in[0];
    const float* theta = (const float*)d_in[1];
    const float* W1    = (const float*)d_in[2];
    const float* b1    = (const float*)d_in[3];
    const float* W2    = (const float*)d_in[4];
    const float* b2    = (const float*)d_in[5];
    float* out = (float*)d_out;

    const size_t w2b = (size_t)EMBED * FFN * 2;          // 8.4 MB bf16 W2
    __hip_bfloat16* Bw = (__hip_bfloat16*)d_ws;
    __hip_bfloat16* h  = (__hip_bfloat16*)((char*)d_ws + w2b);
    const size_t avail = ws_size > w2b ? ws_size - w2b : 0;

    long chunk = (long)((avail / ((size_t)FFN * 2)) & ~2047UL); // mult of 2048 rows
    if (chunk > MTOT) chunk = MTOT;
    if (chunk < 2048) chunk = 2048;

    cvtW2_kernel<<<(EMBED * FFN) / 2048, 256, 0, stream>>>(W2, Bw);

    for (long m0 = 0; m0 < MTOT; m0 += chunk) {
        const long rows = (MTOT - m0 < chunk) ? (MTOT - m0) : chunk;
        hprod2_kernel<<<(int)((rows / STRIP) * 2), 256, 0, stream>>>(
            x, theta, W1, b1, h, (int)m0);
        const int nPm = (int)(rows / BM);                 // multiple of 16
        gemm9_kernel<<<nPm * 8, 256, 0, stream>>>(h, Bw, b2, out, m0, nPm);
    }
}